// Round 2
// baseline (556.136 us; speedup 1.0000x reference)
//
#include <hip/hip_runtime.h>

// ConvCaps (Matrix Capsules w/ EM routing), MI355X fp32.
// One block per output position: 784 blocks x 512 threads (8 waves).
// Thread map: c = wv*4 + (lane&3)  (class, 0..31)
//             sub = (lane>>2)&15   (n-slice, 0..15), each owns 9 n's.
// r lives in registers (E-step writer == M-step reader); LDS only for the
// cross-class softmax. Sub-lane reduction via shfl_xor 4/8/16/32.

namespace {

constexpr int OHW  = 14;
constexpr int NPOS = 4 * OHW * OHW;     // 784
constexpr int NN   = 144;               // 3*3*16
constexpr int CC   = 32;
constexpr int NSUB = 16;
constexpr int KPER = 9;                 // n's per thread
constexpr float LAMB  = 0.01f;
constexpr float EPSF  = 1e-6f;
constexpr float LN2PI = 1.8378770664093453f;
constexpr int PSTR = 20;                // sP row stride (dwords): 16B-aligned, banks spread
constexpr int RS   = 33;                // ln_ap/softmax row stride

__global__ __launch_bounds__(512, 4)
void convcaps_em(const float* __restrict__ x,
                 const float* __restrict__ a,
                 const float* __restrict__ w,        // (144, 32, 4, 4)
                 const float* __restrict__ beta_u,
                 const float* __restrict__ beta_a,
                 const int*   __restrict__ iters_p,
                 float* __restrict__ out_mu,         // (4,14,14,32,16)
                 float* __restrict__ out_a)          // (4,14,14,32,1)
{
  __shared__ __align__(16) float sP[NN * PSTR];
  __shared__ float sA[NN];
  __shared__ float sL[NN * RS];

  const int tid = threadIdx.x;
  const int pos = blockIdx.x;
  const int b   = pos / (OHW * OHW);
  const int rem = pos - b * (OHW * OHW);
  const int oi  = rem / OHW;
  const int oj  = rem - oi * OHW;

  int iters = iters_p[0];
  iters = (iters < 1) ? 1 : (iters > 16 ? 16 : iters);

  // ---- stage pose patch (576 float4) + activations ----
  {
    const int g0 = tid;            // 0..511
    {
      const int n = g0 >> 2, j = g0 & 3;
      const int kh = n / 48, kw = (n >> 4) % 3, bc = n & 15;
      const float4 val = *(const float4*)(x + ((((b * 16 + oi + kh) * 16) + (oj + kw)) * 256 + bc * 16 + j * 4));
      *(float4*)(sP + n * PSTR + j * 4) = val;
    }
    if (tid < 64) {
      const int g = 512 + tid;
      const int n = g >> 2, j = g & 3;
      const int kh = n / 48, kw = (n >> 4) % 3, bc = n & 15;
      const float4 val = *(const float4*)(x + ((((b * 16 + oi + kh) * 16) + (oj + kw)) * 256 + bc * 16 + j * 4));
      *(float4*)(sP + n * PSTR + j * 4) = val;
    }
    if (tid < NN) {
      const int kh = tid / 48, kw = (tid >> 4) % 3, bc = tid & 15;
      sA[tid] = a[(((b * 16 + oi + kh) * 16) + (oj + kw)) * 16 + bc];
    }
  }
  __syncthreads();

  const int lane = tid & 63;
  const int wv   = tid >> 6;                 // 0..7
  const int c    = wv * 4 + (lane & 3);      // 0..31
  const int sub  = (lane >> 2) & 15;         // 0..15
  const int n0   = sub * KPER;
  const float bu = beta_u[c];
  const float ba = beta_a[c];
  const float* __restrict__ wc = w + c * 16; // + n*512

  float r[KPER];
  #pragma unroll
  for (int k = 0; k < KPER; ++k) r[k] = sA[n0 + k] * (1.0f / CC);

  float mu[16], hi[16];

  for (int it = 0; it < iters; ++it) {
    // ---- r_sum over n for class c ----
    float rs = 0.f;
    #pragma unroll
    for (int k = 0; k < KPER; ++k) rs += r[k];
    rs += __shfl_xor(rs, 4);
    rs += __shfl_xor(rs, 8);
    rs += __shfl_xor(rs, 16);
    rs += __shfl_xor(rs, 32);
    const float inv = 1.0f / (rs + EPSF);

    // ---- M-step: S0/S1/S2 over this thread's 9 n's (votes recomputed) ----
    float S0 = 0.f, S1[16], S2[16];
    #pragma unroll
    for (int p = 0; p < 16; ++p) { S1[p] = 0.f; S2[p] = 0.f; }

    #pragma unroll
    for (int k = 0; k < KPER; ++k) {
      const int n = n0 + k;
      const float4* Wp = (const float4*)(wc + n * 512);
      const float4 w0 = Wp[0], w1 = Wp[1], w2 = Wp[2], w3 = Wp[3];
      const float coeff = r[k] * inv;
      S0 += coeff;
      #pragma unroll
      for (int i = 0; i < 4; ++i) {
        const float4 pr = *(const float4*)(sP + n * PSTR + i * 4);
        const float v0 = fmaf(pr.x, w0.x, fmaf(pr.y, w1.x, fmaf(pr.z, w2.x, pr.w * w3.x)));
        const float v1 = fmaf(pr.x, w0.y, fmaf(pr.y, w1.y, fmaf(pr.z, w2.y, pr.w * w3.y)));
        const float v2 = fmaf(pr.x, w0.z, fmaf(pr.y, w1.z, fmaf(pr.z, w2.z, pr.w * w3.z)));
        const float v3 = fmaf(pr.x, w0.w, fmaf(pr.y, w1.w, fmaf(pr.z, w2.w, pr.w * w3.w)));
        S1[4*i+0] = fmaf(coeff, v0, S1[4*i+0]);  S2[4*i+0] = fmaf(coeff * v0, v0, S2[4*i+0]);
        S1[4*i+1] = fmaf(coeff, v1, S1[4*i+1]);  S2[4*i+1] = fmaf(coeff * v1, v1, S2[4*i+1]);
        S1[4*i+2] = fmaf(coeff, v2, S1[4*i+2]);  S2[4*i+2] = fmaf(coeff * v2, v2, S2[4*i+2]);
        S1[4*i+3] = fmaf(coeff, v3, S1[4*i+3]);  S2[4*i+3] = fmaf(coeff * v3, v3, S2[4*i+3]);
      }
    }

    // ---- reduce across the 16 sub-lanes (all lanes keep full sums) ----
    #pragma unroll
    for (int m = 4; m <= 32; m <<= 1) {
      S0 += __shfl_xor(S0, m);
      #pragma unroll
      for (int p = 0; p < 16; ++p) {
        S1[p] += __shfl_xor(S1[p], m);
        S2[p] += __shfl_xor(S2[p], m);
      }
    }

    // ---- per-class stats (redundant across sub-lanes) ----
    float logsum = 0.f;
    #pragma unroll
    for (int p = 0; p < 16; ++p) {
      mu[p] = S1[p];
      float sig = S2[p] - mu[p] * (2.0f * S1[p] - mu[p] * S0) + EPSF;
      sig = fmaxf(sig, 1e-12f);
      logsum += __logf(sig);
      hi[p] = 0.5f / sig;
    }
    const float cost = rs * (16.0f * bu + 0.5f * logsum);
    const float aout = 1.0f / (1.0f + __expf(-LAMB * (ba - cost)));

    if (it == iters - 1) {
      if (sub == 0) {
        float4* om = (float4*)(out_mu + (size_t)pos * 512 + c * 16);
        om[0] = make_float4(mu[0],  mu[1],  mu[2],  mu[3]);
        om[1] = make_float4(mu[4],  mu[5],  mu[6],  mu[7]);
        om[2] = make_float4(mu[8],  mu[9],  mu[10], mu[11]);
        om[3] = make_float4(mu[12], mu[13], mu[14], mu[15]);
        out_a[pos * CC + c] = aout;
      }
    } else {
      // ---- E-step: ln_ap into sL (votes recomputed) ----
      const float kc = __logf(aout + EPSF) - 0.5f * logsum - 8.0f * LN2PI;
      #pragma unroll
      for (int k = 0; k < KPER; ++k) {
        const int n = n0 + k;
        const float4* Wp = (const float4*)(wc + n * 512);
        const float4 w0 = Wp[0], w1 = Wp[1], w2 = Wp[2], w3 = Wp[3];
        float s = 0.f;
        #pragma unroll
        for (int i = 0; i < 4; ++i) {
          const float4 pr = *(const float4*)(sP + n * PSTR + i * 4);
          const float v0 = fmaf(pr.x, w0.x, fmaf(pr.y, w1.x, fmaf(pr.z, w2.x, pr.w * w3.x)));
          const float v1 = fmaf(pr.x, w0.y, fmaf(pr.y, w1.y, fmaf(pr.z, w2.y, pr.w * w3.y)));
          const float v2 = fmaf(pr.x, w0.z, fmaf(pr.y, w1.z, fmaf(pr.z, w2.z, pr.w * w3.z)));
          const float v3 = fmaf(pr.x, w0.w, fmaf(pr.y, w1.w, fmaf(pr.z, w2.w, pr.w * w3.w)));
          float d;
          d = v0 - mu[4*i+0]; s = fmaf(d * d, hi[4*i+0], s);
          d = v1 - mu[4*i+1]; s = fmaf(d * d, hi[4*i+1], s);
          d = v2 - mu[4*i+2]; s = fmaf(d * d, hi[4*i+2], s);
          d = v3 - mu[4*i+3]; s = fmaf(d * d, hi[4*i+3], s);
        }
        sL[n * RS + c] = kc - s;
      }
      __syncthreads();
      // ---- softmax over classes per n, times a_in ----
      if (tid < NN) {
        float xv[32];
        float mx = -3.0e38f;
        #pragma unroll
        for (int q = 0; q < 32; ++q) { xv[q] = sL[tid * RS + q]; mx = fmaxf(mx, xv[q]); }
        float ssum = 0.f;
        #pragma unroll
        for (int q = 0; q < 32; ++q) { xv[q] = __expf(xv[q] - mx); ssum += xv[q]; }
        const float sc = sA[tid] / ssum;
        #pragma unroll
        for (int q = 0; q < 32; ++q) sL[tid * RS + q] = xv[q] * sc;
      }
      __syncthreads();
      // ---- read back this thread's r ----
      #pragma unroll
      for (int k = 0; k < KPER; ++k) r[k] = sL[(n0 + k) * RS + c];
    }
  }
}

} // namespace

extern "C" void kernel_launch(void* const* d_in, const int* in_sizes, int n_in,
                              void* d_out, int out_size, void* d_ws, size_t ws_size,
                              hipStream_t stream) {
  const float* x  = (const float*)d_in[0];
  const float* a  = (const float*)d_in[1];
  const float* w  = (const float*)d_in[2];
  const float* bu = (const float*)d_in[3];
  const float* ba = (const float*)d_in[4];
  const int* iters = (const int*)d_in[5];

  float* out_mu = (float*)d_out;                       // 401408
  float* out_a  = out_mu + (size_t)NPOS * CC * 16;     // 25088

  convcaps_em<<<NPOS, 512, 0, stream>>>(x, a, w, bu, ba, iters, out_mu, out_a);
}

// Round 3
// 133.330 us; speedup vs baseline: 4.1711x; 4.1711x over previous
//
#include <hip/hip_runtime.h>

// ConvCaps (Matrix Capsules w/ EM routing), MI355X fp32.
// One block per output position: 784 blocks x 512 threads (8 waves).
// Thread map: c = wv*4 + (lane&3)  (class, 0..31)
//             sub = lane>>2        (n-slice, 0..15), each owns 9 n's.
// r lives in LDS (writer thread == reader thread, so no extra barriers);
// votes recomputed per pass from LDS poses + L2-resident weights.
// Register budget: __launch_bounds__(512,2) caps at 128 VGPR (observed
// AMD interpretation: arg2=blocks/CU -> 16 waves/CU); round-2's (512,4)
// forced a 64-VGPR cap and catastrophic scratch spill (1.4 GB HBM traffic).

namespace {

constexpr int OHW  = 14;
constexpr int NPOS = 4 * OHW * OHW;     // 784
constexpr int NN   = 144;               // 3*3*16
constexpr int CC   = 32;
constexpr int KPER = 9;                 // n's per thread
constexpr float LAMB  = 0.01f;
constexpr float EPSF  = 1e-6f;
constexpr float LN2PI = 1.8378770664093453f;
constexpr int PSTR = 20;                // sP row stride (dwords): 16B-aligned, banks spread
constexpr int RS   = 33;                // r / ln_ap row stride

__global__ __launch_bounds__(512, 2)
void convcaps_em(const float* __restrict__ x,
                 const float* __restrict__ a,
                 const float* __restrict__ w,        // (144, 32, 4, 4)
                 const float* __restrict__ beta_u,
                 const float* __restrict__ beta_a,
                 const int*   __restrict__ iters_p,
                 float* __restrict__ out_mu,         // (4,14,14,32,16)
                 float* __restrict__ out_a)          // (4,14,14,32,1)
{
  __shared__ __align__(16) float sP[NN * PSTR];
  __shared__ float sA[NN];
  __shared__ float sL[NN * RS];                      // r, then ln_ap, then r ...

  const int tid = threadIdx.x;
  const int pos = blockIdx.x;
  const int b   = pos / (OHW * OHW);
  const int rem = pos - b * (OHW * OHW);
  const int oi  = rem / OHW;
  const int oj  = rem - oi * OHW;

  int iters = iters_p[0];
  iters = (iters < 1) ? 1 : (iters > 16 ? 16 : iters);

  // ---- stage pose patch (576 float4) + activations ----
  {
    {
      const int n = tid >> 2, j = tid & 3;
      const int kh = n / 48, kw = (n >> 4) % 3, bc = n & 15;
      const float4 val = *(const float4*)(x + ((((b * 16 + oi + kh) * 16) + (oj + kw)) * 256 + bc * 16 + j * 4));
      *(float4*)(sP + n * PSTR + j * 4) = val;
    }
    if (tid < 64) {
      const int g = 512 + tid;
      const int n = g >> 2, j = g & 3;
      const int kh = n / 48, kw = (n >> 4) % 3, bc = n & 15;
      const float4 val = *(const float4*)(x + ((((b * 16 + oi + kh) * 16) + (oj + kw)) * 256 + bc * 16 + j * 4));
      *(float4*)(sP + n * PSTR + j * 4) = val;
    }
    if (tid < NN) {
      const int kh = tid / 48, kw = (tid >> 4) % 3, bc = tid & 15;
      sA[tid] = a[(((b * 16 + oi + kh) * 16) + (oj + kw)) * 16 + bc];
    }
  }
  __syncthreads();

  const int lane = tid & 63;
  const int wv   = tid >> 6;                 // 0..7
  const int c    = wv * 4 + (lane & 3);      // 0..31
  const int sub  = lane >> 2;                // 0..15
  const int n0   = sub * KPER;
  const float bu = beta_u[c];
  const float ba = beta_a[c];
  const float* __restrict__ wc = w + c * 16; // + n*512

  // init r[n][c] = a_in[n]/C  (each thread writes exactly its own entries)
  #pragma unroll
  for (int k = 0; k < KPER; ++k) sL[(n0 + k) * RS + c] = sA[n0 + k] * (1.0f / CC);

  float mu[16], hi[16];

  for (int it = 0; it < iters; ++it) {
    // ---- r_sum over n for class c (own entries + cross-sub shuffle) ----
    float rs = 0.f;
    #pragma unroll
    for (int k = 0; k < KPER; ++k) rs += sL[(n0 + k) * RS + c];
    rs += __shfl_xor(rs, 4);
    rs += __shfl_xor(rs, 8);
    rs += __shfl_xor(rs, 16);
    rs += __shfl_xor(rs, 32);
    const float inv = 1.0f / (rs + EPSF);

    // ---- M-step: S0/S1/S2 over this thread's 9 n's (votes recomputed) ----
    float S0 = 0.f, S1[16], S2[16];
    #pragma unroll
    for (int p = 0; p < 16; ++p) { S1[p] = 0.f; S2[p] = 0.f; }

    #pragma unroll 3
    for (int k = 0; k < KPER; ++k) {
      const int n = n0 + k;
      const float4* Wp = (const float4*)(wc + n * 512);
      const float4 w0 = Wp[0], w1 = Wp[1], w2 = Wp[2], w3 = Wp[3];
      const float coeff = sL[n * RS + c] * inv;
      S0 += coeff;
      #pragma unroll
      for (int i = 0; i < 4; ++i) {
        const float4 pr = *(const float4*)(sP + n * PSTR + i * 4);
        const float v0 = fmaf(pr.x, w0.x, fmaf(pr.y, w1.x, fmaf(pr.z, w2.x, pr.w * w3.x)));
        const float v1 = fmaf(pr.x, w0.y, fmaf(pr.y, w1.y, fmaf(pr.z, w2.y, pr.w * w3.y)));
        const float v2 = fmaf(pr.x, w0.z, fmaf(pr.y, w1.z, fmaf(pr.z, w2.z, pr.w * w3.z)));
        const float v3 = fmaf(pr.x, w0.w, fmaf(pr.y, w1.w, fmaf(pr.z, w2.w, pr.w * w3.w)));
        S1[4*i+0] = fmaf(coeff, v0, S1[4*i+0]);  S2[4*i+0] = fmaf(coeff * v0, v0, S2[4*i+0]);
        S1[4*i+1] = fmaf(coeff, v1, S1[4*i+1]);  S2[4*i+1] = fmaf(coeff * v1, v1, S2[4*i+1]);
        S1[4*i+2] = fmaf(coeff, v2, S1[4*i+2]);  S2[4*i+2] = fmaf(coeff * v2, v2, S2[4*i+2]);
        S1[4*i+3] = fmaf(coeff, v3, S1[4*i+3]);  S2[4*i+3] = fmaf(coeff * v3, v3, S2[4*i+3]);
      }
    }

    // ---- reduce across the 16 sub-lanes (all lanes keep full sums) ----
    #pragma unroll
    for (int m = 4; m <= 32; m <<= 1) {
      S0 += __shfl_xor(S0, m);
      #pragma unroll
      for (int p = 0; p < 16; ++p) {
        S1[p] += __shfl_xor(S1[p], m);
        S2[p] += __shfl_xor(S2[p], m);
      }
    }

    // ---- per-class stats (redundant across sub-lanes) ----
    float logsum = 0.f;
    #pragma unroll
    for (int p = 0; p < 16; ++p) {
      mu[p] = S1[p];
      float sig = S2[p] - mu[p] * (2.0f * S1[p] - mu[p] * S0) + EPSF;
      sig = fmaxf(sig, 1e-12f);
      logsum += __logf(sig);
      hi[p] = 0.5f / sig;
    }
    const float cost = rs * (16.0f * bu + 0.5f * logsum);
    const float aout = 1.0f / (1.0f + __expf(-LAMB * (ba - cost)));

    if (it == iters - 1) {
      if (sub == 0) {
        float4* om = (float4*)(out_mu + (size_t)pos * 512 + c * 16);
        om[0] = make_float4(mu[0],  mu[1],  mu[2],  mu[3]);
        om[1] = make_float4(mu[4],  mu[5],  mu[6],  mu[7]);
        om[2] = make_float4(mu[8],  mu[9],  mu[10], mu[11]);
        om[3] = make_float4(mu[12], mu[13], mu[14], mu[15]);
        out_a[pos * CC + c] = aout;
      }
    } else {
      // ---- E-step: ln_ap into sL (votes recomputed; own entries only) ----
      const float kc = __logf(aout + EPSF) - 0.5f * logsum - 8.0f * LN2PI;
      #pragma unroll 3
      for (int k = 0; k < KPER; ++k) {
        const int n = n0 + k;
        const float4* Wp = (const float4*)(wc + n * 512);
        const float4 w0 = Wp[0], w1 = Wp[1], w2 = Wp[2], w3 = Wp[3];
        float s = 0.f;
        #pragma unroll
        for (int i = 0; i < 4; ++i) {
          const float4 pr = *(const float4*)(sP + n * PSTR + i * 4);
          const float v0 = fmaf(pr.x, w0.x, fmaf(pr.y, w1.x, fmaf(pr.z, w2.x, pr.w * w3.x)));
          const float v1 = fmaf(pr.x, w0.y, fmaf(pr.y, w1.y, fmaf(pr.z, w2.y, pr.w * w3.y)));
          const float v2 = fmaf(pr.x, w0.z, fmaf(pr.y, w1.z, fmaf(pr.z, w2.z, pr.w * w3.z)));
          const float v3 = fmaf(pr.x, w0.w, fmaf(pr.y, w1.w, fmaf(pr.z, w2.w, pr.w * w3.w)));
          float d;
          d = v0 - mu[4*i+0]; s = fmaf(d * d, hi[4*i+0], s);
          d = v1 - mu[4*i+1]; s = fmaf(d * d, hi[4*i+1], s);
          d = v2 - mu[4*i+2]; s = fmaf(d * d, hi[4*i+2], s);
          d = v3 - mu[4*i+3]; s = fmaf(d * d, hi[4*i+3], s);
        }
        sL[n * RS + c] = kc - s;
      }
      __syncthreads();
      // ---- softmax over classes per n, times a_in -> new r in sL ----
      if (tid < NN) {
        float xv[32];
        float mx = -3.0e38f;
        #pragma unroll
        for (int q = 0; q < 32; ++q) { xv[q] = sL[tid * RS + q]; mx = fmaxf(mx, xv[q]); }
        float ssum = 0.f;
        #pragma unroll
        for (int q = 0; q < 32; ++q) { xv[q] = __expf(xv[q] - mx); ssum += xv[q]; }
        const float sc = sA[tid] / ssum;
        #pragma unroll
        for (int q = 0; q < 32; ++q) sL[tid * RS + q] = xv[q] * sc;
      }
      __syncthreads();
    }
  }
}

} // namespace

extern "C" void kernel_launch(void* const* d_in, const int* in_sizes, int n_in,
                              void* d_out, int out_size, void* d_ws, size_t ws_size,
                              hipStream_t stream) {
  const float* x  = (const float*)d_in[0];
  const float* a  = (const float*)d_in[1];
  const float* w  = (const float*)d_in[2];
  const float* bu = (const float*)d_in[3];
  const float* ba = (const float*)d_in[4];
  const int* iters = (const int*)d_in[5];

  float* out_mu = (float*)d_out;                       // 401408
  float* out_a  = out_mu + (size_t)NPOS * CC * 16;     // 25088

  convcaps_em<<<NPOS, 512, 0, stream>>>(x, a, w, bu, ba, iters, out_mu, out_a);
}